// Round 9
// baseline (685.087 us; speedup 1.0000x reference)
//
#include <hip/hip_runtime.h>
#include <cstdint>

#define NN 50000
#define NE 600000
#define D 128
#define BS 48               // slots per node (incl. self)
#define NB2 1563            // fine buckets (dst>>5), 32 nodes each
#define NBLK2 1536          // fused grid: 6 blocks/CU x 256 CU, ALL co-resident
#define NDBL 27             // blocks 0..26 each handle one extra bucket (1563-1536)
#define PCAP2 640           // pairs per bucket: mean 384, sigma 19.6 -> 13-sigma margin
#define FA 147              // pass-A blocks: ceil(NE/4096)
#define WB1 16              // W1-pack blocks: 16384/1024
#define XB4 782             // x-convert blocks: ceil(800000/1024)
#define NREP 16             // stats replicas (atomic de-contention)

typedef __attribute__((ext_vector_type(8))) short short8;
typedef __attribute__((ext_vector_type(4))) float f32x4;

static __device__ __forceinline__ unsigned short f2bf(float f) {
  unsigned int u = __float_as_uint(f);
  unsigned int r = (u + 0x7FFFu + ((u >> 16) & 1u)) >> 16;   // RNE
  return (unsigned short)r;
}

// ------------------------------------------------ k_prep: fine edge binning + W1 pack + C/KB + x->bf16
__global__ __launch_bounds__(256) void k_prep(const float* __restrict__ x,
                                              const float* __restrict__ W1,
                                              const float* __restrict__ W2,
                                              const float* __restrict__ Wl,
                                              const float* __restrict__ b2,
                                              const float* __restrict__ bl,
                                              const int* __restrict__ ei,
                                              unsigned short* __restrict__ xb,
                                              unsigned short* __restrict__ W1p,
                                              float* __restrict__ Cf,
                                              float* __restrict__ KBf,
                                              int* __restrict__ gcnt,
                                              unsigned* __restrict__ pairs) {
  __shared__ int histA[NB2], baseA[NB2], curA[NB2];   // 18.3 KB
  int blk = blockIdx.x, t = threadIdx.x;
  if (blk < FA) {                                  // pass A: bin 4096 edges
    for (int i = t; i < NB2; i += 256) histA[i] = 0;
    __syncthreads();
    int e0 = blk * 4096 + t;
    int sreg[16], dreg[16];
#pragma unroll
    for (int i = 0; i < 16; ++i) {                 // single read of src+dst into regs
      int e = e0 + i * 256;
      bool ok = e < NE;
      sreg[i] = ok ? ei[e] : 0;
      dreg[i] = ok ? ei[NE + e] : -1;
      if (ok) atomicAdd(&histA[dreg[i] >> 5], 1);
    }
    __syncthreads();
    for (int i = t; i < NB2; i += 256) {
      int h = histA[i];
      baseA[i] = h ? atomicAdd(&gcnt[i], h) : 0;
      curA[i] = 0;
    }
    __syncthreads();
#pragma unroll
    for (int i = 0; i < 16; ++i) {
      if (dreg[i] >= 0) {
        int b = dreg[i] >> 5;
        int p = baseA[b] + atomicAdd(&curA[b], 1);
        if (p < PCAP2)
          pairs[b * PCAP2 + p] = (unsigned)sreg[i] | ((unsigned)(dreg[i] & 31) << 16);
      }
    }
    return;
  }
  blk -= FA;
  if (blk < WB1) {                                 // pack W1: 4 items/thread
    int base = blk * 1024 + t;
#pragma unroll
    for (int i = 0; i < 4; ++i) {
      int rem = base + i * 256;                    // 0..16383
      int ks = rem >> 12;
      int nf = (rem >> 9) & 7;
      int l  = (rem >> 3) & 63;
      int j  = rem & 7;
      int k = ks * 32 + (l >> 4) * 8 + j;
      int n = nf * 16 + (l & 15);
      W1p[rem] = f2bf(W1[k * D + n]);
    }
    return;
  }
  blk -= WB1;
  if (blk == 0) {                                  // C = W2@Wl (fp32), KB = b2@Wl + bl
    {
      int k = t >> 1, c = t & 1;                   // 256 threads -> 128x2
      const float4* w2r = (const float4*)(W2 + k * D);
      float s = 0.f;
#pragma unroll
      for (int m4 = 0; m4 < 32; ++m4) {
        float4 wv = w2r[m4];
        int m = m4 * 4;
        s += wv.x * Wl[(m + 0) * 2 + c] + wv.y * Wl[(m + 1) * 2 + c] +
             wv.z * Wl[(m + 2) * 2 + c] + wv.w * Wl[(m + 3) * 2 + c];
      }
      Cf[k * 2 + c] = s;
    }
    if (t < 2) {
      float s = bl[t];
      for (int m = 0; m < D; ++m) s += b2[m] * Wl[m * 2 + t];
      KBf[t] = s;
    }
    return;
  }
  blk -= 1;
  {                                                // convert x: 4 uint4/thread
    int64_t base = (int64_t)blk * 1024 + t;
    const float4* xs = (const float4*)x;
#pragma unroll
    for (int i = 0; i < 4; ++i) {
      int64_t idx = base + i * 256;
      if (idx < (int64_t)NN * D / 8) {
        float4 f0 = xs[idx * 2], f1 = xs[idx * 2 + 1];
        uint4 o;
        o.x = (unsigned)f2bf(f0.x) | ((unsigned)f2bf(f0.y) << 16);
        o.y = (unsigned)f2bf(f0.z) | ((unsigned)f2bf(f0.w) << 16);
        o.z = (unsigned)f2bf(f1.x) | ((unsigned)f2bf(f1.y) << 16);
        o.w = (unsigned)f2bf(f1.z) | ((unsigned)f2bf(f1.w) << 16);
        ((uint4*)xb)[idx] = o;
      }
    }
  }
}

// ------------------------------------------------ k_fused: CSR -> gather -> gemm1 -> SOFT GRID BARRIER -> BN + head
// 1536 blocks x 256 threads = EXACTLY 6 blocks/CU x 256 CU -> all co-resident
// (launch_bounds(256,6): VGPR<=85, LDS 13.7KB<=26.6KB, 24<=32 waves) -> a
// device-atomic arrive-and-spin barrier is safe without cooperative launch.
// h1 stays in the MFMA accumulator REGISTERS across the barrier: no h1b
// round-trip, no k_head dispatch. Blocks 0..26 process one extra bucket first
// (h1 via a 217KB spill buffer, head-from-global after the barrier).
__global__ __launch_bounds__(256, 6) void k_fused(const unsigned short* __restrict__ xb,
                                                  const int* __restrict__ gcnt,
                                                  const unsigned* __restrict__ pairs,
                                                  const unsigned short* __restrict__ W1p,
                                                  const float* __restrict__ b1,
                                                  const float* __restrict__ gamma,
                                                  const float* __restrict__ beta,
                                                  const float* __restrict__ Cf,
                                                  const float* __restrict__ KBf,
                                                  unsigned short* __restrict__ h1x,
                                                  float* __restrict__ stats,
                                                  int* __restrict__ gbar,
                                                  float* __restrict__ out) {
  __shared__ uint4 tile[32 * 16];                  // 8 KB: 32 rows x 128 bf16, swizzled
  __shared__ unsigned short cs[32 * BS];           // 3 KB adjacency
  __shared__ int cur[32];
  __shared__ float redS[D], redQ[D];               // stats partials; reused as sc/sh after barrier
  __shared__ float c2s[2 * D];                     // head C columns
  __shared__ float hsum[64];                       // 32 rows x 2 logits
  int t = threadIdx.x, bid = blockIdx.x;
  int w = t >> 6, lane = t & 63;
  int g = lane >> 4, l = lane & 15;
  const uint4* xv = (const uint4*)xb;
  if (t < D) { redS[t] = 0.f; redQ[t] = 0.f; }

  f32x4 acc[4];                                    // pass 0's h1 lives here across the barrier
  int npass = (bid < NDBL) ? 2 : 1;
  for (int pass = npass - 1; pass >= 0; --pass) {
    int b = (pass == 1) ? (NBLK2 + bid) : bid;     // extra bucket first, own bucket last (kept)
    __syncthreads();                               // protect cs/cur/tile reuse across passes
    if (t < 32) cur[t] = 0;
    __syncthreads();

    // ---------- phase 0: CSR build from bucket b
    {
      int cnt = gcnt[b]; if (cnt > PCAP2) cnt = PCAP2;
      for (int i = t; i < cnt; i += 256) {
        unsigned u = pairs[b * PCAP2 + i];
        int dl = (u >> 16) & 31;
        int pos = atomicAdd(&cur[dl], 1);
        if (pos < BS - 1) cs[dl * BS + pos] = (unsigned short)(u & 0xFFFFu);  // slot BS-1 for self
      }
    }
    __syncthreads();

    // ---------- phase 1: gather 8 nodes per wave (2 sub-rounds x 4 nodes), 8 rows in flight
#define GSRC(k) __shfl(((k) < 16 ? cl0 : ((k) < 32 ? cl1 : cl2)), (g << 4) + ((k) & 15))
#define MSK(v, kk) { unsigned m_ = ((kk) < dcap) ? 0xFFFFFFFFu : 0u; \
                     (v).x &= m_; (v).y &= m_; (v).z &= m_; (v).w &= m_; }
#define ACC8(v)                                     \
  { a0 += __uint_as_float((v).x << 16);             \
    a1 += __uint_as_float((v).x & 0xFFFF0000u);     \
    a2 += __uint_as_float((v).y << 16);             \
    a3 += __uint_as_float((v).y & 0xFFFF0000u);     \
    a4 += __uint_as_float((v).z << 16);             \
    a5 += __uint_as_float((v).z & 0xFFFF0000u);     \
    a6 += __uint_as_float((v).w << 16);             \
    a7 += __uint_as_float((v).w & 0xFFFF0000u); }
    for (int sub = 0; sub < 2; ++sub) {
      int dl = (w << 3) + (sub << 2) + g;          // block-local row 0..31
      int node = b * 32 + dl;
      int ec = cur[dl];
      if (ec > BS - 1) ec = BS - 1;                // reserve one slot for self
      int dcap = ec + 1;
      int selfn = (node < NN) ? node : 0;
      int cbase = dl * BS;
      int cl0 = (l < ec) ? (int)cs[cbase + l] : ((l == ec) ? selfn : 0);
      int cl1 = (l + 16 < ec) ? (int)cs[cbase + 16 + l] : ((l + 16 == ec) ? selfn : 0);
      int cl2 = (l + 32 < ec) ? (int)cs[cbase + 32 + l] : ((l + 32 == ec) ? selfn : 0);
      int maxd = dcap;
      maxd = max(maxd, __shfl_xor(maxd, 16));
      maxd = max(maxd, __shfl_xor(maxd, 32));      // wave-uniform trip bound
      float a0 = 0, a1 = 0, a2 = 0, a3 = 0, a4 = 0, a5 = 0, a6 = 0, a7 = 0;
      int nit = (maxd + 7) >> 3;
      for (int it = 0; it < nit; ++it) {
        int k0 = it << 3;
        int i0 = GSRC(k0);
        int i1 = GSRC(k0 + 1);
        int i2 = GSRC(k0 + 2);
        int i3 = GSRC(k0 + 3);
        int i4 = GSRC(k0 + 4);
        int i5 = GSRC(k0 + 5);
        int i6 = GSRC(k0 + 6);
        int i7 = GSRC(k0 + 7);
        uint4 v0 = xv[(unsigned)i0 * 16u + l];     // 8 rows in flight / lane
        uint4 v1 = xv[(unsigned)i1 * 16u + l];
        uint4 v2 = xv[(unsigned)i2 * 16u + l];
        uint4 v3 = xv[(unsigned)i3 * 16u + l];
        uint4 v4 = xv[(unsigned)i4 * 16u + l];
        uint4 v5 = xv[(unsigned)i5 * 16u + l];
        uint4 v6 = xv[(unsigned)i6 * 16u + l];
        uint4 v7 = xv[(unsigned)i7 * 16u + l];
        MSK(v0, k0) MSK(v1, k0 + 1) MSK(v2, k0 + 2) MSK(v3, k0 + 3)
        MSK(v4, k0 + 4) MSK(v5, k0 + 5) MSK(v6, k0 + 6) MSK(v7, k0 + 7)
        ACC8(v0) ACC8(v1) ACC8(v2) ACC8(v3)
        ACC8(v4) ACC8(v5) ACC8(v6) ACC8(v7)
      }
      uint4 o;
      o.x = (unsigned)f2bf(a0) | ((unsigned)f2bf(a1) << 16);
      o.y = (unsigned)f2bf(a2) | ((unsigned)f2bf(a3) << 16);
      o.z = (unsigned)f2bf(a4) | ((unsigned)f2bf(a5) << 16);
      o.w = (unsigned)f2bf(a6) | ((unsigned)f2bf(a7) << 16);
      tile[(dl * 16 + l) ^ (dl & 7)] = o;          // swizzled store (conflict-free)
    }
#undef GSRC
#undef MSK
#undef ACC8
    __syncthreads();                               // phase 2 reads other waves' rows

    // ---------- phase 2: gemm1 — wave (row-half th, nf-half nh); h1 -> acc regs
    {
      int th = w >> 1, nh = w & 1;
      int rbt = th * 16 + l;
      short8 a[4];
#pragma unroll
      for (int ks = 0; ks < 4; ++ks)
        a[ks] = *(const short8*)&tile[(rbt * 16 + ks * 4 + g) ^ (rbt & 7)];

#pragma unroll
      for (int nfl = 0; nfl < 4; ++nfl) { f32x4 z = {0.f, 0.f, 0.f, 0.f}; acc[nfl] = z; }

      const short8* B = (const short8*)W1p;
#pragma unroll
      for (int ks = 0; ks < 4; ++ks)
#pragma unroll
        for (int nfl = 0; nfl < 4; ++nfl) {
          int nf = nh * 4 + nfl;
          acc[nfl] = __builtin_amdgcn_mfma_f32_16x16x32_bf16(a[ks], B[(ks * 8 + nf) * 64 + lane],
                                                             acc[nfl], 0, 0, 0);
        }

#pragma unroll
      for (int nfl = 0; nfl < 4; ++nfl) {
        int colc = (nh * 4 + nfl) * 16 + l;
        float bias = b1[colc];
        float ps = 0.f, pq = 0.f;
#pragma unroll
        for (int r = 0; r < 4; ++r) {
          int row = b * 32 + th * 16 + g * 4 + r;
          float v = fmaxf(acc[nfl][r] + bias, 0.f);
          acc[nfl][r] = v;                         // h1 (f32, pre-BN) kept in regs
          if (row < NN) {
            ps += v; pq += v * v;
            if (pass == 1)                         // extra bucket: spill h1 to compact global
              h1x[(row - NBLK2 * 32) * D + colc] = f2bf(v);
          }
        }
        ps += __shfl_xor(ps, 16); ps += __shfl_xor(ps, 32);
        pq += __shfl_xor(pq, 16); pq += __shfl_xor(pq, 32);
        if (g == 0) { atomicAdd(&redS[colc], ps); atomicAdd(&redQ[colc], pq); }
      }
    }
  }
  __syncthreads();

  // ---------- flush stats (replicated), then soft grid barrier
  {
    int rr = bid & (NREP - 1);
    if (t < D) {
      unsafeAtomicAdd(&stats[rr * 256 + t], redS[t]);
      unsafeAtomicAdd(&stats[rr * 256 + D + t], redQ[t]);
    }
  }
  __threadfence();
  __syncthreads();
  if (t == 0) {
    atomicAdd(gbar, 1);
    while (__hip_atomic_load(gbar, __ATOMIC_ACQUIRE, __HIP_MEMORY_SCOPE_AGENT) < NBLK2)
      __builtin_amdgcn_s_sleep(8);
  }
  __syncthreads();

  // ---------- BN coefficients (redS/redQ reused as sc/sh) + head constants
  if (t < D) {
    float s = 0.f, q = 0.f;
#pragma unroll
    for (int r2 = 0; r2 < NREP; ++r2) {
      s += __hip_atomic_load(&stats[r2 * 256 + t], __ATOMIC_RELAXED, __HIP_MEMORY_SCOPE_AGENT);
      q += __hip_atomic_load(&stats[r2 * 256 + D + t], __ATOMIC_RELAXED, __HIP_MEMORY_SCOPE_AGENT);
    }
    const float inv_n = 1.0f / (float)NN;
    float mean = s * inv_n;
    float var = q * inv_n - mean * mean;
    float sc = gamma[t] * rsqrtf(var + 1e-5f);
    redS[t] = sc;
    redQ[t] = beta[t] - mean * sc;
    float2 cc = ((const float2*)Cf)[t];
    c2s[t] = cc.x; c2s[D + t] = cc.y;
  }
  if (t < 64) hsum[t] = 0.f;
  __syncthreads();

  // ---------- head from registers (own bucket bid): logits = BN(h1)@C + KB
  {
    int th = w >> 1, nh = w & 1;
    float p0[4] = {0.f, 0.f, 0.f, 0.f}, p1[4] = {0.f, 0.f, 0.f, 0.f};
#pragma unroll
    for (int nfl = 0; nfl < 4; ++nfl) {
      int colc = (nh * 4 + nfl) * 16 + l;
      float sc = redS[colc], sh = redQ[colc];
      float cx = c2s[colc], cy = c2s[D + colc];
#pragma unroll
      for (int r = 0; r < 4; ++r) {
        float u = acc[nfl][r] * sc + sh;
        p0[r] += u * cx; p1[r] += u * cy;
      }
    }
#pragma unroll
    for (int off = 1; off <= 8; off <<= 1) {
#pragma unroll
      for (int r = 0; r < 4; ++r) {
        p0[r] += __shfl_xor(p0[r], off);
        p1[r] += __shfl_xor(p1[r], off);
      }
    }
    if (l == 0) {
#pragma unroll
      for (int r = 0; r < 4; ++r) {
        int row2 = th * 16 + g * 4 + r;
        atomicAdd(&hsum[row2 * 2], p0[r]);         // two nh-halves meet here
        atomicAdd(&hsum[row2 * 2 + 1], p1[r]);
      }
    }
  }
  __syncthreads();
  float2 kb = ((const float2*)KBf)[0];
  if (t < 32) {
    int node = bid * 32 + t;
    if (node < NN)
      ((float2*)out)[node] = make_float2(hsum[t * 2] + kb.x, hsum[t * 2 + 1] + kb.y);
  }

  // ---------- head for the extra bucket (from h1x spill)
  if (bid < NDBL) {
#pragma unroll
    for (int rd = 0; rd < 2; ++rd) {
      int nl = rd * 16 + (t >> 4);                 // 0..31
      int node = (NBLK2 + bid) * 32 + nl;
      if (node < NN) {
        uint4 v = ((const uint4*)h1x)[(int64_t)(node - NBLK2 * 32) * 16 + l];
        int k0 = l * 8;
        float e0 = __uint_as_float(v.x << 16), e1 = __uint_as_float(v.x & 0xFFFF0000u);
        float e2 = __uint_as_float(v.y << 16), e3 = __uint_as_float(v.y & 0xFFFF0000u);
        float e4 = __uint_as_float(v.z << 16), e5 = __uint_as_float(v.z & 0xFFFF0000u);
        float e6 = __uint_as_float(v.w << 16), e7 = __uint_as_float(v.w & 0xFFFF0000u);
        float p0 = 0.f, p1 = 0.f;
#define HC(ej, jj) { float u_ = ej * redS[k0 + jj] + redQ[k0 + jj];  \
                     p0 += u_ * c2s[k0 + jj]; p1 += u_ * c2s[D + k0 + jj]; }
        HC(e0, 0) HC(e1, 1) HC(e2, 2) HC(e3, 3) HC(e4, 4) HC(e5, 5) HC(e6, 6) HC(e7, 7)
#undef HC
        p0 += __shfl_xor(p0, 1); p0 += __shfl_xor(p0, 2);
        p0 += __shfl_xor(p0, 4); p0 += __shfl_xor(p0, 8);
        p1 += __shfl_xor(p1, 1); p1 += __shfl_xor(p1, 2);
        p1 += __shfl_xor(p1, 4); p1 += __shfl_xor(p1, 8);
        if (l == 0) ((float2*)out)[node] = make_float2(p0 + kb.x, p1 + kb.y);
      }
    }
  }
}

// ------------------------------------------------ launcher
extern "C" void kernel_launch(void* const* d_in, const int* in_sizes, int n_in,
                              void* d_out, int out_size, void* d_ws, size_t ws_size,
                              hipStream_t stream) {
  const float* x     = (const float*)d_in[0];
  const int*   ei    = (const int*)d_in[1];
  const float* W1    = (const float*)d_in[2];
  const float* b1    = (const float*)d_in[3];
  const float* gamma = (const float*)d_in[4];
  const float* beta  = (const float*)d_in[5];
  const float* W2    = (const float*)d_in[6];
  const float* b2    = (const float*)d_in[7];
  const float* Wl    = (const float*)d_in[8];
  const float* bl    = (const float*)d_in[9];
  float* out = (float*)d_out;

  // workspace layout (~17 MB; h1b replaced by 217 KB spill for 27 extra buckets)
  unsigned short* xb  = (unsigned short*)d_ws;            // NN*D
  unsigned short* W1p = xb + (int64_t)NN * D;             // 16384
  unsigned short* h1x = W1p + 16384;                      // NDBL*32*D (spill, 864 rows)
  float* Cf     = (float*)(h1x + (int64_t)NDBL * 32 * D); // 256 floats
  float* KBf    = Cf + 256;                               // 4 floats
  float* stats  = KBf + 4;                                // NREP*256 floats (replicated S|Q)
  int* gcnt     = (int*)(stats + NREP * 256);             // NB2 ints
  int* gbar     = gcnt + NB2;                             // 1 int (grid barrier)
  unsigned* pairs = (unsigned*)(gbar + 1);                // NB2*PCAP2 (~4 MB)

  hipMemsetAsync(stats, 0, (NREP * 256 + NB2 + 1) * sizeof(int), stream);  // stats + gcnt + gbar
  k_prep<<<FA + WB1 + 1 + XB4, 256, 0, stream>>>(x, W1, W2, Wl, b2, bl, ei,
                                                 xb, W1p, Cf, KBf, gcnt, pairs);
  k_fused<<<NBLK2, 256, 0, stream>>>(xb, gcnt, pairs, W1p, b1, gamma, beta,
                                     Cf, KBf, h1x, stats, gbar, out);
}

// Round 10
// 390.896 us; speedup vs baseline: 1.7526x; 1.7526x over previous
//
#include <hip/hip_runtime.h>
#include <cstdint>

#define NN 50000
#define NE 600000
#define D 128
#define BS 48               // slots per node (incl. self)
#define NB2 1563            // fine buckets (dst>>5), 32 nodes each
#define NBLK2 1536          // fused grid: 6 blocks/CU x 256 CU, ALL co-resident
#define NDBL 27             // blocks 0..26 each handle one extra bucket (1563-1536)
#define PCAP2 640           // pairs per bucket: mean 384, sigma 19.6 -> 13-sigma margin
#define FA 147              // pass-A blocks: ceil(NE/4096)
#define WB1 16              // W1-pack blocks: 16384/1024
#define XB4 782             // x-convert blocks: ceil(800000/1024)
#define NREP 16             // stats replicas (atomic de-contention)

typedef __attribute__((ext_vector_type(8))) short short8;
typedef __attribute__((ext_vector_type(4))) float f32x4;

static __device__ __forceinline__ unsigned short f2bf(float f) {
  unsigned int u = __float_as_uint(f);
  unsigned int r = (u + 0x7FFFu + ((u >> 16) & 1u)) >> 16;   // RNE
  return (unsigned short)r;
}

// ------------------------------------------------ k_prep: fine edge binning + W1 pack + C/KB + x->bf16
__global__ __launch_bounds__(256) void k_prep(const float* __restrict__ x,
                                              const float* __restrict__ W1,
                                              const float* __restrict__ W2,
                                              const float* __restrict__ Wl,
                                              const float* __restrict__ b2,
                                              const float* __restrict__ bl,
                                              const int* __restrict__ ei,
                                              unsigned short* __restrict__ xb,
                                              unsigned short* __restrict__ W1p,
                                              float* __restrict__ Cf,
                                              float* __restrict__ KBf,
                                              int* __restrict__ gcnt,
                                              unsigned* __restrict__ pairs) {
  __shared__ int histA[NB2], baseA[NB2], curA[NB2];   // 18.3 KB
  int blk = blockIdx.x, t = threadIdx.x;
  if (blk < FA) {                                  // pass A: bin 4096 edges
    for (int i = t; i < NB2; i += 256) histA[i] = 0;
    __syncthreads();
    int e0 = blk * 4096 + t;
    int sreg[16], dreg[16];
#pragma unroll
    for (int i = 0; i < 16; ++i) {                 // single read of src+dst into regs
      int e = e0 + i * 256;
      bool ok = e < NE;
      sreg[i] = ok ? ei[e] : 0;
      dreg[i] = ok ? ei[NE + e] : -1;
      if (ok) atomicAdd(&histA[dreg[i] >> 5], 1);
    }
    __syncthreads();
    for (int i = t; i < NB2; i += 256) {
      int h = histA[i];
      baseA[i] = h ? atomicAdd(&gcnt[i], h) : 0;
      curA[i] = 0;
    }
    __syncthreads();
#pragma unroll
    for (int i = 0; i < 16; ++i) {
      if (dreg[i] >= 0) {
        int b = dreg[i] >> 5;
        int p = baseA[b] + atomicAdd(&curA[b], 1);
        if (p < PCAP2)
          pairs[b * PCAP2 + p] = (unsigned)sreg[i] | ((unsigned)(dreg[i] & 31) << 16);
      }
    }
    return;
  }
  blk -= FA;
  if (blk < WB1) {                                 // pack W1: 4 items/thread
    int base = blk * 1024 + t;
#pragma unroll
    for (int i = 0; i < 4; ++i) {
      int rem = base + i * 256;                    // 0..16383
      int ks = rem >> 12;
      int nf = (rem >> 9) & 7;
      int l  = (rem >> 3) & 63;
      int j  = rem & 7;
      int k = ks * 32 + (l >> 4) * 8 + j;
      int n = nf * 16 + (l & 15);
      W1p[rem] = f2bf(W1[k * D + n]);
    }
    return;
  }
  blk -= WB1;
  if (blk == 0) {                                  // C = W2@Wl (fp32), KB = b2@Wl + bl
    {
      int k = t >> 1, c = t & 1;                   // 256 threads -> 128x2
      const float4* w2r = (const float4*)(W2 + k * D);
      float s = 0.f;
#pragma unroll
      for (int m4 = 0; m4 < 32; ++m4) {
        float4 wv = w2r[m4];
        int m = m4 * 4;
        s += wv.x * Wl[(m + 0) * 2 + c] + wv.y * Wl[(m + 1) * 2 + c] +
             wv.z * Wl[(m + 2) * 2 + c] + wv.w * Wl[(m + 3) * 2 + c];
      }
      Cf[k * 2 + c] = s;
    }
    if (t < 2) {
      float s = bl[t];
      for (int m = 0; m < D; ++m) s += b2[m] * Wl[m * 2 + t];
      KBf[t] = s;
    }
    return;
  }
  blk -= 1;
  {                                                // convert x: 4 uint4/thread
    int64_t base = (int64_t)blk * 1024 + t;
    const float4* xs = (const float4*)x;
#pragma unroll
    for (int i = 0; i < 4; ++i) {
      int64_t idx = base + i * 256;
      if (idx < (int64_t)NN * D / 8) {
        float4 f0 = xs[idx * 2], f1 = xs[idx * 2 + 1];
        uint4 o;
        o.x = (unsigned)f2bf(f0.x) | ((unsigned)f2bf(f0.y) << 16);
        o.y = (unsigned)f2bf(f0.z) | ((unsigned)f2bf(f0.w) << 16);
        o.z = (unsigned)f2bf(f1.x) | ((unsigned)f2bf(f1.y) << 16);
        o.w = (unsigned)f2bf(f1.z) | ((unsigned)f2bf(f1.w) << 16);
        ((uint4*)xb)[idx] = o;
      }
    }
  }
}

// ------------------------------------------------ k_fused: CSR -> gather -> gemm1 -> soft barrier -> BN + head
// R9 structure with the barrier poll FIXED: spin on a RELAXED agent-scope
// atomic load (reads through to the coherence point, NO L2 invalidate) +
// s_sleep(16) backoff. R9's ACQUIRE poll emitted an L2 invalidate per poll ->
// continuous L2 flush storm (FETCH +61MB, WRITE +109MB, 10x slowdown).
// Release side stays: __threadfence() before the arrive-add. Stats are re-read
// after the barrier with relaxed agent-scope atomic loads (coherence point).
__global__ __launch_bounds__(256, 6) void k_fused(const unsigned short* __restrict__ xb,
                                                  const int* __restrict__ gcnt,
                                                  const unsigned* __restrict__ pairs,
                                                  const unsigned short* __restrict__ W1p,
                                                  const float* __restrict__ b1,
                                                  const float* __restrict__ gamma,
                                                  const float* __restrict__ beta,
                                                  const float* __restrict__ Cf,
                                                  const float* __restrict__ KBf,
                                                  unsigned short* __restrict__ h1x,
                                                  float* __restrict__ stats,
                                                  int* __restrict__ gbar,
                                                  float* __restrict__ out) {
  __shared__ uint4 tile[32 * 16];                  // 8 KB: 32 rows x 128 bf16, swizzled
  __shared__ unsigned short cs[32 * BS];           // 3 KB adjacency
  __shared__ int cur[32];
  __shared__ float redS[D], redQ[D];               // stats partials; reused as sc/sh after barrier
  __shared__ float c2s[2 * D];                     // head C columns
  __shared__ float hsum[64];                       // 32 rows x 2 logits
  int t = threadIdx.x, bid = blockIdx.x;
  int w = t >> 6, lane = t & 63;
  int g = lane >> 4, l = lane & 15;
  const uint4* xv = (const uint4*)xb;
  if (t < D) { redS[t] = 0.f; redQ[t] = 0.f; }

  f32x4 acc[4];                                    // pass 0's h1 lives here across the barrier
  int npass = (bid < NDBL) ? 2 : 1;
  for (int pass = npass - 1; pass >= 0; --pass) {
    int b = (pass == 1) ? (NBLK2 + bid) : bid;     // extra bucket first, own bucket last (kept)
    __syncthreads();                               // protect cs/cur/tile reuse across passes
    if (t < 32) cur[t] = 0;
    __syncthreads();

    // ---------- phase 0: CSR build from bucket b
    {
      int cnt = gcnt[b]; if (cnt > PCAP2) cnt = PCAP2;
      for (int i = t; i < cnt; i += 256) {
        unsigned u = pairs[b * PCAP2 + i];
        int dl = (u >> 16) & 31;
        int pos = atomicAdd(&cur[dl], 1);
        if (pos < BS - 1) cs[dl * BS + pos] = (unsigned short)(u & 0xFFFFu);  // slot BS-1 for self
      }
    }
    __syncthreads();

    // ---------- phase 1: gather 8 nodes per wave (2 sub-rounds x 4 nodes), 8 rows in flight
#define GSRC(k) __shfl(((k) < 16 ? cl0 : ((k) < 32 ? cl1 : cl2)), (g << 4) + ((k) & 15))
#define MSK(v, kk) { unsigned m_ = ((kk) < dcap) ? 0xFFFFFFFFu : 0u; \
                     (v).x &= m_; (v).y &= m_; (v).z &= m_; (v).w &= m_; }
#define ACC8(v)                                     \
  { a0 += __uint_as_float((v).x << 16);             \
    a1 += __uint_as_float((v).x & 0xFFFF0000u);     \
    a2 += __uint_as_float((v).y << 16);             \
    a3 += __uint_as_float((v).y & 0xFFFF0000u);     \
    a4 += __uint_as_float((v).z << 16);             \
    a5 += __uint_as_float((v).z & 0xFFFF0000u);     \
    a6 += __uint_as_float((v).w << 16);             \
    a7 += __uint_as_float((v).w & 0xFFFF0000u); }
    for (int sub = 0; sub < 2; ++sub) {
      int dl = (w << 3) + (sub << 2) + g;          // block-local row 0..31
      int node = b * 32 + dl;
      int ec = cur[dl];
      if (ec > BS - 1) ec = BS - 1;                // reserve one slot for self
      int dcap = ec + 1;
      int selfn = (node < NN) ? node : 0;
      int cbase = dl * BS;
      int cl0 = (l < ec) ? (int)cs[cbase + l] : ((l == ec) ? selfn : 0);
      int cl1 = (l + 16 < ec) ? (int)cs[cbase + 16 + l] : ((l + 16 == ec) ? selfn : 0);
      int cl2 = (l + 32 < ec) ? (int)cs[cbase + 32 + l] : ((l + 32 == ec) ? selfn : 0);
      int maxd = dcap;
      maxd = max(maxd, __shfl_xor(maxd, 16));
      maxd = max(maxd, __shfl_xor(maxd, 32));      // wave-uniform trip bound
      float a0 = 0, a1 = 0, a2 = 0, a3 = 0, a4 = 0, a5 = 0, a6 = 0, a7 = 0;
      int nit = (maxd + 7) >> 3;
      for (int it = 0; it < nit; ++it) {
        int k0 = it << 3;
        int i0 = GSRC(k0);
        int i1 = GSRC(k0 + 1);
        int i2 = GSRC(k0 + 2);
        int i3 = GSRC(k0 + 3);
        int i4 = GSRC(k0 + 4);
        int i5 = GSRC(k0 + 5);
        int i6 = GSRC(k0 + 6);
        int i7 = GSRC(k0 + 7);
        uint4 v0 = xv[(unsigned)i0 * 16u + l];     // 8 rows in flight / lane
        uint4 v1 = xv[(unsigned)i1 * 16u + l];
        uint4 v2 = xv[(unsigned)i2 * 16u + l];
        uint4 v3 = xv[(unsigned)i3 * 16u + l];
        uint4 v4 = xv[(unsigned)i4 * 16u + l];
        uint4 v5 = xv[(unsigned)i5 * 16u + l];
        uint4 v6 = xv[(unsigned)i6 * 16u + l];
        uint4 v7 = xv[(unsigned)i7 * 16u + l];
        MSK(v0, k0) MSK(v1, k0 + 1) MSK(v2, k0 + 2) MSK(v3, k0 + 3)
        MSK(v4, k0 + 4) MSK(v5, k0 + 5) MSK(v6, k0 + 6) MSK(v7, k0 + 7)
        ACC8(v0) ACC8(v1) ACC8(v2) ACC8(v3)
        ACC8(v4) ACC8(v5) ACC8(v6) ACC8(v7)
      }
      uint4 o;
      o.x = (unsigned)f2bf(a0) | ((unsigned)f2bf(a1) << 16);
      o.y = (unsigned)f2bf(a2) | ((unsigned)f2bf(a3) << 16);
      o.z = (unsigned)f2bf(a4) | ((unsigned)f2bf(a5) << 16);
      o.w = (unsigned)f2bf(a6) | ((unsigned)f2bf(a7) << 16);
      tile[(dl * 16 + l) ^ (dl & 7)] = o;          // swizzled store (conflict-free)
    }
#undef GSRC
#undef MSK
#undef ACC8
    __syncthreads();                               // phase 2 reads other waves' rows

    // ---------- phase 2: gemm1 — wave (row-half th, nf-half nh); h1 -> acc regs
    {
      int th = w >> 1, nh = w & 1;
      int rbt = th * 16 + l;
      short8 a[4];
#pragma unroll
      for (int ks = 0; ks < 4; ++ks)
        a[ks] = *(const short8*)&tile[(rbt * 16 + ks * 4 + g) ^ (rbt & 7)];

#pragma unroll
      for (int nfl = 0; nfl < 4; ++nfl) { f32x4 z = {0.f, 0.f, 0.f, 0.f}; acc[nfl] = z; }

      const short8* B = (const short8*)W1p;
#pragma unroll
      for (int ks = 0; ks < 4; ++ks)
#pragma unroll
        for (int nfl = 0; nfl < 4; ++nfl) {
          int nf = nh * 4 + nfl;
          acc[nfl] = __builtin_amdgcn_mfma_f32_16x16x32_bf16(a[ks], B[(ks * 8 + nf) * 64 + lane],
                                                             acc[nfl], 0, 0, 0);
        }

#pragma unroll
      for (int nfl = 0; nfl < 4; ++nfl) {
        int colc = (nh * 4 + nfl) * 16 + l;
        float bias = b1[colc];
        float ps = 0.f, pq = 0.f;
#pragma unroll
        for (int r = 0; r < 4; ++r) {
          int row = b * 32 + th * 16 + g * 4 + r;
          float v = fmaxf(acc[nfl][r] + bias, 0.f);
          acc[nfl][r] = v;                         // h1 (f32, pre-BN) kept in regs
          if (row < NN) {
            ps += v; pq += v * v;
            if (pass == 1)                         // extra bucket: spill h1 to compact global
              h1x[(row - NBLK2 * 32) * D + colc] = f2bf(v);
          }
        }
        ps += __shfl_xor(ps, 16); ps += __shfl_xor(ps, 32);
        pq += __shfl_xor(pq, 16); pq += __shfl_xor(pq, 32);
        if (g == 0) { atomicAdd(&redS[colc], ps); atomicAdd(&redQ[colc], pq); }
      }
    }
  }
  __syncthreads();

  // ---------- flush stats (replicated), then soft grid barrier (relaxed poll)
  {
    int rr = bid & (NREP - 1);
    if (t < D) {
      unsafeAtomicAdd(&stats[rr * 256 + t], redS[t]);
      unsafeAtomicAdd(&stats[rr * 256 + D + t], redQ[t]);
    }
  }
  __threadfence();                                 // release: stats visible before arrive
  __syncthreads();
  if (t == 0) {
    atomicAdd(gbar, 1);
    while (__hip_atomic_load(gbar, __ATOMIC_RELAXED, __HIP_MEMORY_SCOPE_AGENT) < NBLK2)
      __builtin_amdgcn_s_sleep(16);                // relaxed poll: NO L2 invalidate (R9 lesson)
  }
  __syncthreads();

  // ---------- BN coefficients (redS/redQ reused as sc/sh) + head constants
  if (t < D) {
    float s = 0.f, q = 0.f;
#pragma unroll
    for (int r2 = 0; r2 < NREP; ++r2) {            // atomic relaxed loads: read coherence point
      s += __hip_atomic_load(&stats[r2 * 256 + t], __ATOMIC_RELAXED, __HIP_MEMORY_SCOPE_AGENT);
      q += __hip_atomic_load(&stats[r2 * 256 + D + t], __ATOMIC_RELAXED, __HIP_MEMORY_SCOPE_AGENT);
    }
    const float inv_n = 1.0f / (float)NN;
    float mean = s * inv_n;
    float var = q * inv_n - mean * mean;
    float sc = gamma[t] * rsqrtf(var + 1e-5f);
    redS[t] = sc;
    redQ[t] = beta[t] - mean * sc;
    float2 cc = ((const float2*)Cf)[t];
    c2s[t] = cc.x; c2s[D + t] = cc.y;
  }
  if (t < 64) hsum[t] = 0.f;
  __syncthreads();

  // ---------- head from registers (own bucket bid): logits = BN(h1)@C + KB
  {
    int th = w >> 1, nh = w & 1;
    float p0[4] = {0.f, 0.f, 0.f, 0.f}, p1[4] = {0.f, 0.f, 0.f, 0.f};
#pragma unroll
    for (int nfl = 0; nfl < 4; ++nfl) {
      int colc = (nh * 4 + nfl) * 16 + l;
      float sc = redS[colc], sh = redQ[colc];
      float cx = c2s[colc], cy = c2s[D + colc];
#pragma unroll
      for (int r = 0; r < 4; ++r) {
        float u = acc[nfl][r] * sc + sh;
        p0[r] += u * cx; p1[r] += u * cy;
      }
    }
#pragma unroll
    for (int off = 1; off <= 8; off <<= 1) {
#pragma unroll
      for (int r = 0; r < 4; ++r) {
        p0[r] += __shfl_xor(p0[r], off);
        p1[r] += __shfl_xor(p1[r], off);
      }
    }
    if (l == 0) {
#pragma unroll
      for (int r = 0; r < 4; ++r) {
        int row2 = th * 16 + g * 4 + r;
        atomicAdd(&hsum[row2 * 2], p0[r]);         // two nh-halves meet here
        atomicAdd(&hsum[row2 * 2 + 1], p1[r]);
      }
    }
  }
  __syncthreads();
  float2 kb = ((const float2*)KBf)[0];
  if (t < 32) {
    int node = bid * 32 + t;
    if (node < NN)
      ((float2*)out)[node] = make_float2(hsum[t * 2] + kb.x, hsum[t * 2 + 1] + kb.y);
  }

  // ---------- head for the extra bucket (from h1x spill)
  if (bid < NDBL) {
#pragma unroll
    for (int rd = 0; rd < 2; ++rd) {
      int nl = rd * 16 + (t >> 4);                 // 0..31
      int node = (NBLK2 + bid) * 32 + nl;
      if (node < NN) {
        uint4 v = ((const uint4*)h1x)[(int64_t)(node - NBLK2 * 32) * 16 + l];
        int k0 = l * 8;
        float e0 = __uint_as_float(v.x << 16), e1 = __uint_as_float(v.x & 0xFFFF0000u);
        float e2 = __uint_as_float(v.y << 16), e3 = __uint_as_float(v.y & 0xFFFF0000u);
        float e4 = __uint_as_float(v.z << 16), e5 = __uint_as_float(v.z & 0xFFFF0000u);
        float e6 = __uint_as_float(v.w << 16), e7 = __uint_as_float(v.w & 0xFFFF0000u);
        float p0 = 0.f, p1 = 0.f;
#define HC(ej, jj) { float u_ = ej * redS[k0 + jj] + redQ[k0 + jj];  \
                     p0 += u_ * c2s[k0 + jj]; p1 += u_ * c2s[D + k0 + jj]; }
        HC(e0, 0) HC(e1, 1) HC(e2, 2) HC(e3, 3) HC(e4, 4) HC(e5, 5) HC(e6, 6) HC(e7, 7)
#undef HC
        p0 += __shfl_xor(p0, 1); p0 += __shfl_xor(p0, 2);
        p0 += __shfl_xor(p0, 4); p0 += __shfl_xor(p0, 8);
        p1 += __shfl_xor(p1, 1); p1 += __shfl_xor(p1, 2);
        p1 += __shfl_xor(p1, 4); p1 += __shfl_xor(p1, 8);
        if (l == 0) ((float2*)out)[node] = make_float2(p0 + kb.x, p1 + kb.y);
      }
    }
  }
}

// ------------------------------------------------ launcher
extern "C" void kernel_launch(void* const* d_in, const int* in_sizes, int n_in,
                              void* d_out, int out_size, void* d_ws, size_t ws_size,
                              hipStream_t stream) {
  const float* x     = (const float*)d_in[0];
  const int*   ei    = (const int*)d_in[1];
  const float* W1    = (const float*)d_in[2];
  const float* b1    = (const float*)d_in[3];
  const float* gamma = (const float*)d_in[4];
  const float* beta  = (const float*)d_in[5];
  const float* W2    = (const float*)d_in[6];
  const float* b2    = (const float*)d_in[7];
  const float* Wl    = (const float*)d_in[8];
  const float* bl    = (const float*)d_in[9];
  float* out = (float*)d_out;

  // workspace layout (~17 MB; h1b replaced by 217 KB spill for 27 extra buckets)
  unsigned short* xb  = (unsigned short*)d_ws;            // NN*D
  unsigned short* W1p = xb + (int64_t)NN * D;             // 16384
  unsigned short* h1x = W1p + 16384;                      // NDBL*32*D (spill, 864 rows)
  float* Cf     = (float*)(h1x + (int64_t)NDBL * 32 * D); // 256 floats
  float* KBf    = Cf + 256;                               // 4 floats
  float* stats  = KBf + 4;                                // NREP*256 floats (replicated S|Q)
  int* gcnt     = (int*)(stats + NREP * 256);             // NB2 ints
  int* gbar     = gcnt + NB2;                             // 1 int (grid barrier)
  unsigned* pairs = (unsigned*)(gbar + 1);                // NB2*PCAP2 (~4 MB)

  hipMemsetAsync(stats, 0, (NREP * 256 + NB2 + 1) * sizeof(int), stream);  // stats + gcnt + gbar
  k_prep<<<FA + WB1 + 1 + XB4, 256, 0, stream>>>(x, W1, W2, Wl, b2, bl, ei,
                                                 xb, W1p, Cf, KBf, gcnt, pairs);
  k_fused<<<NBLK2, 256, 0, stream>>>(xb, gcnt, pairs, W1p, b1, gamma, beta,
                                     Cf, KBf, h1x, stats, gbar, out);
}

// Round 12
// 70.574 us; speedup vs baseline: 9.7074x; 5.5388x over previous
//
#include <hip/hip_runtime.h>
#include <cstdint>

#define NN 50000
#define NE 600000
#define D 128
#define BS 48               // slots per node (incl. self)
#define NB2 1563            // fine buckets (dst>>5), 32 nodes each
#define PCAP2 640           // pairs per bucket: mean 384, sigma 19.6 -> 13-sigma margin
#define FA 147              // pass-A blocks: ceil(NE/4096)
#define WB1 16              // W1-pack blocks: 16384/1024
#define XB4 782             // x-convert blocks: ceil(800000/1024)
#define NREP 16             // stats replicas (atomic de-contention)

typedef __attribute__((ext_vector_type(8))) short short8;
typedef __attribute__((ext_vector_type(4))) float f32x4;

static __device__ __forceinline__ unsigned short f2bf(float f) {
  unsigned int u = __float_as_uint(f);
  unsigned int r = (u + 0x7FFFu + ((u >> 16) & 1u)) >> 16;   // RNE
  return (unsigned short)r;
}

// ------------------------------------------------ k_prep: fine edge binning + W1 pack + C/KB + x->bf16
//  [0,FA)            : bin edges into 1563 fine buckets (32 dst nodes each); edges reg-cached
//  [FA,FA+WB1)       : pack W1 into MFMA B-fragment layout
//  [FA+WB1]          : C = W2@Wl (128x2), KB = b2@Wl + bl  (head collapse: gemm2 is linear)
//  [FA+WB1+1, ...)   : convert x -> bf16 (row-major)
__global__ __launch_bounds__(256) void k_prep(const float* __restrict__ x,
                                              const float* __restrict__ W1,
                                              const float* __restrict__ W2,
                                              const float* __restrict__ Wl,
                                              const float* __restrict__ b2,
                                              const float* __restrict__ bl,
                                              const int* __restrict__ ei,
                                              unsigned short* __restrict__ xb,
                                              unsigned short* __restrict__ W1p,
                                              float* __restrict__ Cf,
                                              float* __restrict__ KBf,
                                              int* __restrict__ gcnt,
                                              unsigned* __restrict__ pairs) {
  __shared__ int histA[NB2], baseA[NB2], curA[NB2];   // 18.3 KB
  int blk = blockIdx.x, t = threadIdx.x;
  if (blk < FA) {                                  // pass A: bin 4096 edges
    for (int i = t; i < NB2; i += 256) histA[i] = 0;
    __syncthreads();
    int e0 = blk * 4096 + t;
    int sreg[16], dreg[16];
#pragma unroll
    for (int i = 0; i < 16; ++i) {                 // single read of src+dst into regs
      int e = e0 + i * 256;
      bool ok = e < NE;
      sreg[i] = ok ? ei[e] : 0;
      dreg[i] = ok ? ei[NE + e] : -1;
      if (ok) atomicAdd(&histA[dreg[i] >> 5], 1);
    }
    __syncthreads();
    for (int i = t; i < NB2; i += 256) {
      int h = histA[i];
      baseA[i] = h ? atomicAdd(&gcnt[i], h) : 0;
      curA[i] = 0;
    }
    __syncthreads();
#pragma unroll
    for (int i = 0; i < 16; ++i) {
      if (dreg[i] >= 0) {
        int b = dreg[i] >> 5;
        int p = baseA[b] + atomicAdd(&curA[b], 1);
        if (p < PCAP2)
          pairs[b * PCAP2 + p] = (unsigned)sreg[i] | ((unsigned)(dreg[i] & 31) << 16);
      }
    }
    return;
  }
  blk -= FA;
  if (blk < WB1) {                                 // pack W1: 4 items/thread
    int base = blk * 1024 + t;
#pragma unroll
    for (int i = 0; i < 4; ++i) {
      int rem = base + i * 256;                    // 0..16383
      int ks = rem >> 12;
      int nf = (rem >> 9) & 7;
      int l  = (rem >> 3) & 63;
      int j  = rem & 7;
      int k = ks * 32 + (l >> 4) * 8 + j;
      int n = nf * 16 + (l & 15);
      W1p[rem] = f2bf(W1[k * D + n]);
    }
    return;
  }
  blk -= WB1;
  if (blk == 0) {                                  // C = W2@Wl (fp32), KB = b2@Wl + bl
    {
      int k = t >> 1, c = t & 1;                   // 256 threads -> 128x2
      const float4* w2r = (const float4*)(W2 + k * D);
      float s = 0.f;
#pragma unroll
      for (int m4 = 0; m4 < 32; ++m4) {
        float4 wv = w2r[m4];
        int m = m4 * 4;
        s += wv.x * Wl[(m + 0) * 2 + c] + wv.y * Wl[(m + 1) * 2 + c] +
             wv.z * Wl[(m + 2) * 2 + c] + wv.w * Wl[(m + 3) * 2 + c];
      }
      Cf[k * 2 + c] = s;
    }
    if (t < 2) {
      float s = bl[t];
      for (int m = 0; m < D; ++m) s += b2[m] * Wl[m * 2 + t];
      KBf[t] = s;
    }
    return;
  }
  blk -= 1;
  {                                                // convert x: 4 uint4/thread
    int64_t base = (int64_t)blk * 1024 + t;
    const float4* xs = (const float4*)x;
#pragma unroll
    for (int i = 0; i < 4; ++i) {
      int64_t idx = base + i * 256;
      if (idx < (int64_t)NN * D / 8) {
        float4 f0 = xs[idx * 2], f1 = xs[idx * 2 + 1];
        uint4 o;
        o.x = (unsigned)f2bf(f0.x) | ((unsigned)f2bf(f0.y) << 16);
        o.y = (unsigned)f2bf(f0.z) | ((unsigned)f2bf(f0.w) << 16);
        o.z = (unsigned)f2bf(f1.x) | ((unsigned)f2bf(f1.y) << 16);
        o.w = (unsigned)f2bf(f1.z) | ((unsigned)f2bf(f1.w) << 16);
        ((uint4*)xb)[idx] = o;
      }
    }
  }
}

// ------------------------------------------------ k_fusedA: CSR-in-LDS -> gather (-> LDS tile) -> gemm1
// 1563 blocks x 256 threads, 32 nodes/block (8/wave). VERIFIED best (R8, 70.6us).
// NO __launch_bounds__ second arg: (256,6) provably squeezes VGPR to 40 and
// spills the 8-in-flight gather buffer (~320 B/thread scratch; R3/R9-R11).
// Kernel boundary (not an in-kernel barrier) is the cross-XCD coherence point
// for stats: in-kernel soft barriers raced (R11 post-timing divergence).
// Phase 0: CSR from OWN fine bucket. Phase 1: one node per 16-lane group,
// 8 rows in flight/lane, self folded into index regs, select-before-load
// masking; h0 -> XOR-swizzled LDS tile. Phase 2: MFMA gemm1,
// wave = (row-half, nf-half); h1 -> global; stats -> replicated atomics.
__global__ __launch_bounds__(256) void k_fusedA(const unsigned short* __restrict__ xb,
                                                const int* __restrict__ gcnt,
                                                const unsigned* __restrict__ pairs,
                                                const unsigned short* __restrict__ W1p,
                                                const float* __restrict__ b1,
                                                unsigned short* __restrict__ h1b,
                                                float* __restrict__ stats) {
  __shared__ uint4 tile[32 * 16];                  // 8 KB: 32 rows x 128 bf16, swizzled
  __shared__ unsigned short cs[32 * BS];           // 3 KB adjacency
  __shared__ int cur[32];
  __shared__ float redS[D], redQ[D];
  int t = threadIdx.x, b = blockIdx.x;
  if (t < D) { redS[t] = 0.f; redQ[t] = 0.f; }
  if (t < 32) cur[t] = 0;
  __syncthreads();

  // ---------- phase 0: CSR build from this block's own fine bucket
  {
    int cnt = gcnt[b]; if (cnt > PCAP2) cnt = PCAP2;
    for (int i = t; i < cnt; i += 256) {
      unsigned u = pairs[b * PCAP2 + i];
      int dl = (u >> 16) & 31;
      int pos = atomicAdd(&cur[dl], 1);
      if (pos < BS - 1) cs[dl * BS + pos] = (unsigned short)(u & 0xFFFFu);  // slot BS-1 for self
    }
  }
  __syncthreads();

  int w = t >> 6, lane = t & 63;
  int g = lane >> 4, l = lane & 15;
  const uint4* xv = (const uint4*)xb;

  // ---------- phase 1: gather 8 nodes per wave (2 sub-rounds x 4 nodes)
#define GSRC(k) __shfl(((k) < 16 ? cl0 : ((k) < 32 ? cl1 : cl2)), (g << 4) + ((k) & 15))
#define MSK(v, kk) { unsigned m_ = ((kk) < dcap) ? 0xFFFFFFFFu : 0u; \
                     (v).x &= m_; (v).y &= m_; (v).z &= m_; (v).w &= m_; }
#define ACC8(v)                                     \
  { a0 += __uint_as_float((v).x << 16);             \
    a1 += __uint_as_float((v).x & 0xFFFF0000u);     \
    a2 += __uint_as_float((v).y << 16);             \
    a3 += __uint_as_float((v).y & 0xFFFF0000u);     \
    a4 += __uint_as_float((v).z << 16);             \
    a5 += __uint_as_float((v).z & 0xFFFF0000u);     \
    a6 += __uint_as_float((v).w << 16);             \
    a7 += __uint_as_float((v).w & 0xFFFF0000u); }
  for (int sub = 0; sub < 2; ++sub) {
    int dl = (w << 3) + (sub << 2) + g;            // block-local row 0..31
    int node = b * 32 + dl;
    int ec = cur[dl];                              // edge count (LDS broadcast)
    if (ec > BS - 1) ec = BS - 1;                  // reserve one slot for self
    int dcap = ec + 1;                             // slots incl. self
    int selfn = (node < NN) ? node : 0;
    int cbase = dl * BS;
    int cl0 = (l < ec) ? (int)cs[cbase + l]
                       : ((l == ec) ? selfn : 0);            // self folded in
    int cl1 = (l + 16 < ec) ? (int)cs[cbase + 16 + l]
                            : ((l + 16 == ec) ? selfn : 0);
    int cl2 = (l + 32 < ec) ? (int)cs[cbase + 32 + l]
                            : ((l + 32 == ec) ? selfn : 0);
    int maxd = dcap;
    maxd = max(maxd, __shfl_xor(maxd, 16));
    maxd = max(maxd, __shfl_xor(maxd, 32));        // wave-uniform trip bound
    float a0 = 0, a1 = 0, a2 = 0, a3 = 0, a4 = 0, a5 = 0, a6 = 0, a7 = 0;
    int nit = (maxd + 7) >> 3;                     // 8 slots per iteration
    for (int it = 0; it < nit; ++it) {
      int k0 = it << 3;
      int i0 = GSRC(k0);
      int i1 = GSRC(k0 + 1);
      int i2 = GSRC(k0 + 2);
      int i3 = GSRC(k0 + 3);
      int i4 = GSRC(k0 + 4);
      int i5 = GSRC(k0 + 5);
      int i6 = GSRC(k0 + 6);
      int i7 = GSRC(k0 + 7);
      uint4 v0 = xv[(unsigned)i0 * 16u + l];       // 8 rows in flight / lane
      uint4 v1 = xv[(unsigned)i1 * 16u + l];
      uint4 v2 = xv[(unsigned)i2 * 16u + l];
      uint4 v3 = xv[(unsigned)i3 * 16u + l];
      uint4 v4 = xv[(unsigned)i4 * 16u + l];
      uint4 v5 = xv[(unsigned)i5 * 16u + l];
      uint4 v6 = xv[(unsigned)i6 * 16u + l];
      uint4 v7 = xv[(unsigned)i7 * 16u + l];
      MSK(v0, k0) MSK(v1, k0 + 1) MSK(v2, k0 + 2) MSK(v3, k0 + 3)
      MSK(v4, k0 + 4) MSK(v5, k0 + 5) MSK(v6, k0 + 6) MSK(v7, k0 + 7)
      ACC8(v0) ACC8(v1) ACC8(v2) ACC8(v3)
      ACC8(v4) ACC8(v5) ACC8(v6) ACC8(v7)
    }
    uint4 o;
    o.x = (unsigned)f2bf(a0) | ((unsigned)f2bf(a1) << 16);
    o.y = (unsigned)f2bf(a2) | ((unsigned)f2bf(a3) << 16);
    o.z = (unsigned)f2bf(a4) | ((unsigned)f2bf(a5) << 16);
    o.w = (unsigned)f2bf(a6) | ((unsigned)f2bf(a7) << 16);
    tile[(dl * 16 + l) ^ (dl & 7)] = o;            // swizzled store (conflict-free)
  }
#undef GSRC
#undef MSK
#undef ACC8
  __syncthreads();                                 // phase 2 reads other waves' rows

  // ---------- phase 2: gemm1 — wave (row-half th, nf-half nh) of the 32-row tile
  {
    int th = w >> 1, nh = w & 1;
    int rbt = th * 16 + l;
    short8 a[4];
#pragma unroll
    for (int ks = 0; ks < 4; ++ks)
      a[ks] = *(const short8*)&tile[(rbt * 16 + ks * 4 + g) ^ (rbt & 7)];

    f32x4 acc[4];
#pragma unroll
    for (int nfl = 0; nfl < 4; ++nfl) { f32x4 z = {0.f, 0.f, 0.f, 0.f}; acc[nfl] = z; }

    const short8* B = (const short8*)W1p;
#pragma unroll
    for (int ks = 0; ks < 4; ++ks)
#pragma unroll
      for (int nfl = 0; nfl < 4; ++nfl) {
        int nf = nh * 4 + nfl;
        acc[nfl] = __builtin_amdgcn_mfma_f32_16x16x32_bf16(a[ks], B[(ks * 8 + nf) * 64 + lane],
                                                           acc[nfl], 0, 0, 0);
      }

#pragma unroll
    for (int nfl = 0; nfl < 4; ++nfl) {
      int colc = (nh * 4 + nfl) * 16 + l;
      float bias = b1[colc];
      float ps = 0.f, pq = 0.f;
#pragma unroll
      for (int r = 0; r < 4; ++r) {
        int row = b * 32 + th * 16 + g * 4 + r;
        float v = fmaxf(acc[nfl][r] + bias, 0.f);
        if (row < NN) {
          h1b[(int64_t)row * D + colc] = f2bf(v);
          ps += v; pq += v * v;
        }
      }
      ps += __shfl_xor(ps, 16); ps += __shfl_xor(ps, 32);
      pq += __shfl_xor(pq, 16); pq += __shfl_xor(pq, 32);
      if (g == 0) { atomicAdd(&redS[colc], ps); atomicAdd(&redQ[colc], pq); }
    }
  }
  __syncthreads();
  {
    int r = blockIdx.x & (NREP - 1);               // replicated stats: 16x less line contention
    if (t < D) {
      unsafeAtomicAdd(&stats[r * 256 + t], redS[t]);
      unsafeAtomicAdd(&stats[r * 256 + D + t], redQ[t]);
    }
  }
}

// ------------------------------------------------ k_head: BN-fold + collapsed linear head (fp32)
// logits = BN(h1) @ C + KB.  Grid matches k_fusedA (1563 x 32 nodes) so h1b
// rows are read on the same XCD's L2 that wrote them.
__global__ __launch_bounds__(256) void k_head(const unsigned short* __restrict__ h1b,
                                              const float* __restrict__ stats,
                                              const float* __restrict__ gamma,
                                              const float* __restrict__ beta,
                                              const float* __restrict__ Cf,
                                              const float* __restrict__ KBf,
                                              float* __restrict__ out) {
  __shared__ float sc_s[D], sh_s[D];
  __shared__ float2 c2_s[D];
  int t = threadIdx.x;
  if (t < D) {
    float s = 0.f, q = 0.f;
#pragma unroll
    for (int r = 0; r < NREP; ++r) {               // sum the 16 replicas
      s += stats[r * 256 + t];
      q += stats[r * 256 + D + t];
    }
    const float inv_n = 1.0f / (float)NN;
    float mean = s * inv_n;
    float var = q * inv_n - mean * mean;
    float sc = gamma[t] * rsqrtf(var + 1e-5f);
    sc_s[t] = sc;
    sh_s[t] = beta[t] - mean * sc;
    c2_s[t] = ((const float2*)Cf)[t];
  }
  __syncthreads();
  float2 kb = ((const float2*)KBf)[0];
  int l = t & 15;
  int k0 = l * 8;
#pragma unroll
  for (int rd = 0; rd < 2; ++rd) {
    int node = blockIdx.x * 32 + rd * 16 + (t >> 4);
    if (node < NN) {
      uint4 v = ((const uint4*)h1b)[(int64_t)node * 16 + l];
      float e0 = __uint_as_float(v.x << 16), e1 = __uint_as_float(v.x & 0xFFFF0000u);
      float e2 = __uint_as_float(v.y << 16), e3 = __uint_as_float(v.y & 0xFFFF0000u);
      float e4 = __uint_as_float(v.z << 16), e5 = __uint_as_float(v.z & 0xFFFF0000u);
      float e6 = __uint_as_float(v.w << 16), e7 = __uint_as_float(v.w & 0xFFFF0000u);
      float p0 = 0.f, p1 = 0.f;
#define HC(ej, jj) { float u_ = ej * sc_s[k0 + jj] + sh_s[k0 + jj];  \
                     float2 c_ = c2_s[k0 + jj];                      \
                     p0 += u_ * c_.x; p1 += u_ * c_.y; }
      HC(e0, 0) HC(e1, 1) HC(e2, 2) HC(e3, 3) HC(e4, 4) HC(e5, 5) HC(e6, 6) HC(e7, 7)
#undef HC
      p0 += __shfl_xor(p0, 1); p0 += __shfl_xor(p0, 2);
      p0 += __shfl_xor(p0, 4); p0 += __shfl_xor(p0, 8);
      p1 += __shfl_xor(p1, 1); p1 += __shfl_xor(p1, 2);
      p1 += __shfl_xor(p1, 4); p1 += __shfl_xor(p1, 8);
      if (l == 0) ((float2*)out)[node] = make_float2(p0 + kb.x, p1 + kb.y);
    }
  }
}

// ------------------------------------------------ launcher
extern "C" void kernel_launch(void* const* d_in, const int* in_sizes, int n_in,
                              void* d_out, int out_size, void* d_ws, size_t ws_size,
                              hipStream_t stream) {
  const float* x     = (const float*)d_in[0];
  const int*   ei    = (const int*)d_in[1];
  const float* W1    = (const float*)d_in[2];
  const float* b1    = (const float*)d_in[3];
  const float* gamma = (const float*)d_in[4];
  const float* beta  = (const float*)d_in[5];
  const float* W2    = (const float*)d_in[6];
  const float* b2    = (const float*)d_in[7];
  const float* Wl    = (const float*)d_in[8];
  const float* bl    = (const float*)d_in[9];
  float* out = (float*)d_out;

  // workspace layout (~30 MB)
  unsigned short* xb  = (unsigned short*)d_ws;            // NN*D
  unsigned short* h1b = xb + (int64_t)NN * D;             // NN*D
  unsigned short* W1p = h1b + (int64_t)NN * D;            // 16384
  float* Cf     = (float*)(W1p + 16384);                  // 256 floats (C = W2@Wl as float2[128])
  float* KBf    = Cf + 256;                               // 4 floats (2 used)
  float* stats  = KBf + 4;                                // NREP*256 floats (replicated S|Q)
  int* gcnt     = (int*)(stats + NREP * 256);             // NB2 ints (contiguous: one memset)
  unsigned* pairs = (unsigned*)(gcnt + NB2);              // NB2*PCAP2 (~4 MB)

  hipMemsetAsync(stats, 0, (NREP * 256 + NB2) * sizeof(float), stream);  // stats + gcnt
  k_prep<<<FA + WB1 + 1 + XB4, 256, 0, stream>>>(x, W1, W2, Wl, b2, bl, ei,
                                                 xb, W1p, Cf, KBf, gcnt, pairs);
  k_fusedA<<<NB2, 256, 0, stream>>>(xb, gcnt, pairs, W1p, b1, h1b, stats);
  k_head<<<NB2, 256, 0, stream>>>(h1b, stats, gamma, beta, Cf, KBf, out);
}